// Round 17
// baseline (630.002 us; speedup 1.0000x reference)
//
#include <hip/hip_runtime.h>

// r15 LESSON: in-kernel split-K combine (atomicAdd counter + __threadfence)
// REGRESSED 626 -> 1280 us (device-scope fence = L2 thrash on 8-XCD gfx950).
// r11 LESSON: 256^2 coarse counted-vmcnt BIG regressed (lost 5-blocks/CU
// cross-block overlap). Keep: 128^2 BIG + separate-dispatch reduction.

typedef unsigned short ushort_t;
typedef unsigned int uint32;
typedef __attribute__((ext_vector_type(8))) unsigned short ushort8;
typedef __attribute__((ext_vector_type(8))) __bf16 bf16x8;
typedef __attribute__((ext_vector_type(4))) float f32x4;

__device__ __forceinline__ ushort_t f2b(float f) {
    union { float f; uint32 u; } v; v.f = f;
    uint32 r = v.u + 0x7fffu + ((v.u >> 16) & 1u);
    return (ushort_t)(r >> 16);
}
__device__ __forceinline__ float b2f(ushort_t b) {
    union { uint32 u; float f; } v; v.u = ((uint32)b) << 16;
    return v.f;
}
__device__ __forceinline__ float sigm(float x) { return 1.f / (1.f + __expf(-x)); }

__device__ __forceinline__ void gload_lds16(const void* g, void* l) {
    __builtin_amdgcn_global_load_lds(
        (__attribute__((address_space(1))) void*)g,
        (__attribute__((address_space(3))) void*)l, 16, 0, 0);
}

// epilogues
constexpr int EPI_RELU  = 1;  // bf16 relu(acc+bias) -> obf (q for s==2)
constexpr int EPI_FQ    = 2;  // merged: col<1024 feat=acc+bias+res; col>=1024 q=relu(acc+bias)
constexpr int EPI_SIG   = 3;  // rowsum sigmoid(acc) -> dsum[(by*2+wc)][z*256+row]
constexpr int EPI_XG    = 4;  // bf16 acc -> obf[z*oB + row*ldo + col]  (XGt)
constexpr int EPI_NEGCW = 5;  // bf16 -acc*cw[z*128+col] -> obf (Htn)
constexpr int EPI_Y     = 6;  // bf16 res + acc -> obf (catb slice)
constexpr int EPI_OUTT  = 7;  // fp32 acc+bias[row]; row=outchan, col=pixel -> NCHW coalesced

struct GemmP {
    const ushort_t* A; const ushort_t* B;
    const ushort_t* A2; const ushort_t* B2;     // AMODE==2 second source (gk >= 256)
    long long aBatch, bBatch, a2Batch, b2Batch;
    int lda, ldb, lda2, ldb2;
    int Ksub, kSplit, dil;
    const float* bias;
    const ushort_t* res; long long resBatch; int ldres;
    ushort_t* obf; long long oBatch; int ldo;
    ushort_t* obf2;
    float* of32;
    const float* cw;
    const float* rscale;   // AMODE==2: per-row scale of A2 (d factor)
    float* dsum;
    const ushort_t* zpage;
};

// ---------------------------------------------------------------------------
// BIG implicit-GEMM body (9 dilated conv taps + conv1x1 identity tap),
// m97-style global_load_lds staging, split-K=5, 128x128 tile, BK=64.
// LDS image S[r][g] = G[r][g ^ (r&7)] via pre-swizzled per-lane source;
// reads apply the same XOR (conflict-free, r3-verified). Tap-aligned split-K
// chunks (2048 = 2 taps): tap geometry hoisted to per-tap outer loop. OOB
// rows use an 8KB zero page. bf16 partials.
// ---------------------------------------------------------------------------
__device__ __forceinline__ void big_body(ushort_t* aT, ushort_t* bT,
                                         const GemmP& p, int bx, int by, int z) {
    const int tid = threadIdx.x;
    const int m0 = bx * 128, n0 = by * 128;
    const int lane = tid & 63, wid = tid >> 6;
    const int l15 = lane & 15, l16 = lane >> 4;
    const int wr = wid >> 1, wc = wid & 1;
    const int lrow = lane >> 3;
    const int sgran = (lane & 7) ^ lrow;

    int ayy[4], axx[4];
    const ushort_t* aBase[4];
    const ushort_t* bBase[4];
#pragma unroll
    for (int i = 0; i < 4; ++i) {
        int row = wid * 32 + i * 8 + lrow;
        int m = m0 + row;
        int bb = m >> 8;
        ayy[i] = (m >> 4) & 15; axx[i] = m & 15;
        aBase[i] = p.A + (long long)bb * 262144 + sgran * 8;
        bBase[i] = p.B + (long long)(n0 + row) * p.ldb + sgran * 8;
    }

    f32x4 acc[4][4];
#pragma unroll
    for (int i = 0; i < 4; ++i)
#pragma unroll
        for (int j = 0; j < 4; ++j) acc[i][j] = (f32x4){0.f, 0.f, 0.f, 0.f};

    const int gk0 = z * p.kSplit;          // tap-aligned
    const int ntap = p.Ksub >> 10;
    for (int ti = 0; ti < ntap; ++ti) {
        const int tap = (gk0 >> 10) + ti;
        int dy = 0, dx = 0;
        if (tap < 9) { int ky = tap / 3; dy = (ky - 1) * p.dil; dx = (tap - ky * 3 - 1) * p.dil; }
        const ushort_t* gaA[4];
        const ushort_t* gaB[4];
#pragma unroll
        for (int i = 0; i < 4; ++i) {
            int iy = ayy[i] + dy, ix = axx[i] + dx;
            bool ok = ((unsigned)iy < 16u) && ((unsigned)ix < 16u);
            gaA[i] = ok ? (aBase[i] + (((iy << 4) + ix) << 10)) : (p.zpage + sgran * 8);
            gaB[i] = bBase[i] + (tap << 10);
        }
        for (int kk = 0; kk < 16; ++kk) {
            const int kin = kk << 6;
#pragma unroll
            for (int i = 0; i < 4; ++i)
                gload_lds16(gaA[i] + kin, &aT[(wid * 32 + i * 8) * 64]);
#pragma unroll
            for (int i = 0; i < 4; ++i)
                gload_lds16(gaB[i] + kin, &bT[(wid * 32 + i * 8) * 64]);
            asm volatile("s_waitcnt vmcnt(0)" ::: "memory");
            __syncthreads();
#pragma unroll
            for (int ks = 0; ks < 2; ++ks) {
                bf16x8 af[4], bfr[4];
#pragma unroll
                for (int mi = 0; mi < 4; ++mi) {
                    int rr = wr * 64 + mi * 16 + l15;
                    int cc = (ks * 32 + l16 * 8) ^ ((rr & 7) << 3);
                    af[mi] = __builtin_bit_cast(bf16x8, *(const ushort8*)&aT[rr * 64 + cc]);
                }
#pragma unroll
                for (int ni = 0; ni < 4; ++ni) {
                    int rr = wc * 64 + ni * 16 + l15;
                    int cc = (ks * 32 + l16 * 8) ^ ((rr & 7) << 3);
                    bfr[ni] = __builtin_bit_cast(bf16x8, *(const ushort8*)&bT[rr * 64 + cc]);
                }
#pragma unroll
                for (int mi = 0; mi < 4; ++mi)
#pragma unroll
                    for (int ni = 0; ni < 4; ++ni)
                        acc[mi][ni] = __builtin_amdgcn_mfma_f32_16x16x32_bf16(af[mi], bfr[ni], acc[mi][ni], 0, 0, 0);
            }
            __syncthreads();
        }
    }
#pragma unroll
    for (int mi = 0; mi < 4; ++mi)
#pragma unroll
        for (int ni = 0; ni < 4; ++ni) {
            int gcol = n0 + wc * 64 + ni * 16 + l15;
            int growb = m0 + wr * 64 + mi * 16 + l16 * 4;
#pragma unroll
            for (int r = 0; r < 4; ++r)
                p.obf[(long long)z * p.oBatch + (long long)(growb + r) * 256 + gcol] =
                    f2b(acc[mi][ni][r]);
        }
}

// ---------------------------------------------------------------------------
// Generic 4-wave MFMA GEMM body (explicit bx/by/z so merged kernels can
// remap grid planes to roles): C = A.B^T, bf16 in, fp32 acc.
// AMODE==0: single source. AMODE==2: dual source. AMODE==3: A K-scaled by cw.
// ---------------------------------------------------------------------------
template<int BM, int BN, int AMODE, int EPI>
__device__ __forceinline__ void gemm_body(ushort_t* aT, ushort_t* bT,
                                          const GemmP& p, int bx, int by, int z) {
    constexpr int APASS = BM / 32, BPASS = BN / 32;
    constexpr int MFRAG = BM / 32, NFRAG = BN / 32;
    const int tid = threadIdx.x;
    const int m0 = bx * BM, n0 = by * BN;
    const int lane = tid & 63, wid = tid >> 6;
    const int l15 = lane & 15, l16 = lane >> 4;
    const int wr = wid >> 1, wc = wid & 1;
    const int srow = tid >> 3, scol = (tid & 7) * 8;
    const int swcol = scol ^ ((srow & 7) << 3);

    const ushort_t* aptr[APASS];
    const ushort_t* bptr[BPASS];
    const ushort_t* aptr2[APASS];
    const ushort_t* bptr2[BPASS];
    float rsA[APASS];
#pragma unroll
    for (int pi = 0; pi < APASS; ++pi)
        aptr[pi] = p.A + (long long)z * p.aBatch +
                   (long long)(m0 + pi * 32 + srow) * p.lda + scol;
#pragma unroll
    for (int pi = 0; pi < BPASS; ++pi)
        bptr[pi] = p.B + (long long)z * p.bBatch +
                   (long long)(n0 + pi * 32 + srow) * p.ldb + scol;
    if constexpr (AMODE == 2) {
#pragma unroll
        for (int pi = 0; pi < APASS; ++pi) {
            aptr2[pi] = p.A2 + (long long)z * p.a2Batch +
                        (long long)(m0 + pi * 32 + srow) * p.lda2 + scol;
            rsA[pi] = p.rscale[z * 256 + m0 + pi * 32 + srow];
        }
#pragma unroll
        for (int pi = 0; pi < BPASS; ++pi)
            bptr2[pi] = p.B2 + (long long)z * p.b2Batch +
                        (long long)(n0 + pi * 32 + srow) * p.ldb2 + scol;
    }

    f32x4 acc[MFRAG][NFRAG];
#pragma unroll
    for (int i = 0; i < MFRAG; ++i)
#pragma unroll
        for (int j = 0; j < NFRAG; ++j) acc[i][j] = (f32x4){0.f, 0.f, 0.f, 0.f};

    ushort8 ar[APASS], br[BPASS];
    auto ldg = [&](int gk) {
        if (AMODE == 2 && gk >= 256) {
            int g2 = gk - 256;
#pragma unroll
            for (int pi = 0; pi < APASS; ++pi) {
                ushort8 t8 = *(const ushort8*)(aptr2[pi] + g2);
#pragma unroll
                for (int k = 0; k < 8; ++k) t8[k] = f2b(b2f(t8[k]) * rsA[pi]);
                ar[pi] = t8;
            }
#pragma unroll
            for (int pi = 0; pi < BPASS; ++pi) br[pi] = *(const ushort8*)(bptr2[pi] + g2);
        } else if constexpr (AMODE == 3) {
#pragma unroll
            for (int pi = 0; pi < APASS; ++pi) {
                ushort8 t8 = *(const ushort8*)(aptr[pi] + gk);
#pragma unroll
                for (int k = 0; k < 8; ++k)
                    t8[k] = f2b(b2f(t8[k]) * p.cw[(z << 7) + gk + scol + k]);
                ar[pi] = t8;
            }
#pragma unroll
            for (int pi = 0; pi < BPASS; ++pi) br[pi] = *(const ushort8*)(bptr[pi] + gk);
        } else {
#pragma unroll
            for (int pi = 0; pi < APASS; ++pi) ar[pi] = *(const ushort8*)(aptr[pi] + gk);
#pragma unroll
            for (int pi = 0; pi < BPASS; ++pi) br[pi] = *(const ushort8*)(bptr[pi] + gk);
        }
    };

    const int gk0 = z * p.kSplit;
    ldg(gk0);
    const int iters = p.Ksub >> 6;
    for (int it = 0; it < iters; ++it) {
#pragma unroll
        for (int pi = 0; pi < APASS; ++pi)
            *(ushort8*)&aT[(pi * 32 + srow) * 64 + swcol] = ar[pi];
#pragma unroll
        for (int pi = 0; pi < BPASS; ++pi)
            *(ushort8*)&bT[(pi * 32 + srow) * 64 + swcol] = br[pi];
        __syncthreads();
        if (it + 1 < iters) ldg(gk0 + (it + 1) * 64);
#pragma unroll
        for (int ks = 0; ks < 2; ++ks) {
            bf16x8 af[MFRAG], bfr[NFRAG];
#pragma unroll
            for (int mi = 0; mi < MFRAG; ++mi) {
                int rr = wr * (BM / 2) + mi * 16 + l15;
                int cc = (ks * 32 + l16 * 8) ^ ((rr & 7) << 3);
                af[mi] = __builtin_bit_cast(bf16x8, *(const ushort8*)&aT[rr * 64 + cc]);
            }
#pragma unroll
            for (int ni = 0; ni < NFRAG; ++ni) {
                int rr = wc * (BN / 2) + ni * 16 + l15;
                int cc = (ks * 32 + l16 * 8) ^ ((rr & 7) << 3);
                bfr[ni] = __builtin_bit_cast(bf16x8, *(const ushort8*)&bT[rr * 64 + cc]);
            }
#pragma unroll
            for (int mi = 0; mi < MFRAG; ++mi)
#pragma unroll
                for (int ni = 0; ni < NFRAG; ++ni)
                    acc[mi][ni] = __builtin_amdgcn_mfma_f32_16x16x32_bf16(af[mi], bfr[ni], acc[mi][ni], 0, 0, 0);
        }
        __syncthreads();
    }

    // ---------------- epilogue ----------------
#pragma unroll
    for (int mi = 0; mi < MFRAG; ++mi) {
        if constexpr (EPI == EPI_SIG) {
#pragma unroll
            for (int r = 0; r < 4; ++r) {
                float sv = 0.f;
#pragma unroll
                for (int ni = 0; ni < NFRAG; ++ni) sv += sigm(acc[mi][ni][r]);
                sv += __shfl_xor(sv, 1); sv += __shfl_xor(sv, 2);
                sv += __shfl_xor(sv, 4); sv += __shfl_xor(sv, 8);
                if (l15 == 0) {
                    int grow = m0 + wr * (BM / 2) + mi * 16 + l16 * 4 + r;
                    int q8 = by * 2 + wc;  // disjoint slot -> deterministic
                    p.dsum[q8 * 16384 + z * 256 + grow] = sv;
                }
            }
        } else {
#pragma unroll
            for (int ni = 0; ni < NFRAG; ++ni) {
                int gcol = n0 + wc * (BN / 2) + ni * 16 + l15;
                int growb = m0 + wr * (BM / 2) + mi * 16 + l16 * 4;
#pragma unroll
                for (int r = 0; r < 4; ++r) {
                    int grow = growb + r;
                    float v = acc[mi][ni][r];
                    if constexpr (EPI == EPI_RELU) {
                        v += p.bias[gcol]; v = fmaxf(v, 0.f);
                        p.obf[(long long)grow * p.ldo + gcol] = f2b(v);
                    } else if constexpr (EPI == EPI_FQ) {
                        v += p.bias[gcol];
                        if (gcol < 1024) {   // uniform per tile (1024%BN==0)
                            v += b2f(p.res[(long long)grow * 1024 + gcol]);
                            p.obf[(long long)grow * 1024 + gcol] = f2b(v);
                        } else {
                            v = fmaxf(v, 0.f);
                            p.obf2[(long long)grow * 128 + (gcol - 1024)] = f2b(v);
                        }
                    } else if constexpr (EPI == EPI_XG) {
                        p.obf[(long long)z * p.oBatch + (long long)grow * p.ldo + gcol] = f2b(v);
                    } else if constexpr (EPI == EPI_NEGCW) {
                        v *= -p.cw[z * 128 + gcol];
                        p.obf[(long long)z * p.oBatch + (long long)grow * p.ldo + gcol] = f2b(v);
                    } else if constexpr (EPI == EPI_Y) {
                        v = b2f(p.res[(long long)z * p.resBatch + (long long)grow * p.ldres + gcol]) + v;
                        p.obf[(long long)z * p.oBatch + (long long)grow * p.ldo + gcol] = f2b(v);
                    } else if constexpr (EPI == EPI_OUTT) {
                        v += p.bias[grow];               // row = out-channel
                        int bb = gcol >> 8, px = gcol & 255;
                        p.of32[((long long)bb * 1024 + grow) * 256 + px] = v;  // coalesced over px
                    }
                }
            }
        }
    }
}

template<int BM, int BN, int AMODE, int EPI>
__global__ __launch_bounds__(256) void gemm_k(GemmP p) {
    __shared__ __align__(16) ushort_t aT[BM * 64];
    __shared__ __align__(16) ushort_t bT[BN * 64];
    gemm_body<BM, BN, AMODE, EPI>(aT, bT, p, blockIdx.x, blockIdx.y, blockIdx.z);
}

// avg/max pool + channel-weight MLP body (256 threads; LDS reused)
__device__ __forceinline__ void pool_body(void* lds, int b, const ushort_t* f,
                                          const float* aw, const float* mw,
                                          float* cw) {
    float* sa = (float*)lds;
    float* sm = sa + 256;
    int t = threadIdx.x;
    float s = 0.f, m = -3.4e38f;
    const ushort_t* base = f + (long long)b * 65536 + t;
    for (int px = 0; px < 256; ++px) { float v = b2f(base[px * 256]); s += v; m = fmaxf(m, v); }
    sa[t] = s * (1.f / 256.f);
    sm[t] = m;
    __syncthreads();
    if (t < 128) {
        float s1 = 0.f, s2 = 0.f;
        const float* a = aw + t * 256; const float* w = mw + t * 256;
        for (int c = 0; c < 256; ++c) { s1 += sa[c] * a[c]; s2 += sm[c] * w[c]; }
        s1 = fmaxf(s1, 0.f); s2 = fmaxf(s2, 0.f);
        cw[b * 128 + t] = sigm(s1 + s2);
    }
}

// pscale body: d = rsqrt(sum of 8 dsum slots); dscale (f32) + transposed Pt
__device__ __forceinline__ void pscale_body(int jh, int b,
                                            const ushort_t* q, const float* dsum8,
                                            float* dscale, ushort_t* Pt) {
    __shared__ ushort_t t[128][130];
    __shared__ float dd[128];
    int j0 = jh * 128;
    int tid = threadIdx.x;
    if (tid < 128) {
        int pix = b * 256 + j0 + tid;
        float s = 0.f;
#pragma unroll
        for (int qs = 0; qs < 8; ++qs) s += dsum8[qs * 16384 + pix];
        float r = rsqrtf(s);
        dd[tid] = r;
        dscale[pix] = r;
    }
    __syncthreads();
    int jr = tid >> 7, m = tid & 127;
    for (int i = 0; i < 64; ++i) {
        int j = i * 2 + jr;
        long long qi = ((long long)(b * 256 + j0 + j)) * 128 + m;
        t[j][m] = f2b(dd[j] * b2f(q[qi]));
    }
    __syncthreads();
    for (int i = 0; i < 64; ++i) {
        int mm = i * 2 + jr;
        Pt[((long long)b << 15) + (mm << 8) + j0 + m] = t[m][mm];
    }
}

// BIG (z<5) ∥ sigxg_{prev} (z in 5..12) ∥ Y_{prev2} (z in 13..16).
__global__ __launch_bounds__(256) void k_big_sig_y(GemmP pb, GemmP ps, GemmP px,
                                                   GemmP py) {
    __shared__ __align__(16) ushort_t lds[2 * 128 * 64];
    int z = blockIdx.z;
    if (z < 5) { big_body(lds, lds + 8192, pb, blockIdx.x, blockIdx.y, z); return; }
    if (z < 13) {
        int flat = (z - 5) * 256 + blockIdx.y * 128 + blockIdx.x;  // 0..2047
        int bx = flat & 3, by = (flat >> 2) & 3, bz = flat >> 4;
        if (bz < 64) gemm_body<64, 64, 3, EPI_SIG>(lds, lds + 4096, ps, bx, by, bz);
        else         gemm_body<64, 64, 0, EPI_XG>(lds, lds + 4096, px, bx, by, bz - 64);
        return;
    }
    int flat = (z - 13) * 256 + blockIdx.y * 128 + blockIdx.x;     // 0..1023
    gemm_body<64, 64, 2, EPI_Y>(lds, lds + 4096, py, flat & 3, (flat >> 2) & 3, flat >> 4);
}

// FQ GEMM (y<9, 128^2) ∥ poolcw (y==9, x<64) ∥ Htn_{prev} (y in 10..13).
__global__ __launch_bounds__(256) void k_fqpool_htn(GemmP pf, GemmP ph,
                                                    const float* aw, const float* mw,
                                                    float* cw) {
    __shared__ __align__(16) ushort_t lds[2 * 128 * 64];
    int y = blockIdx.y;
    if (y < 9) { gemm_body<128, 128, 0, EPI_FQ>(lds, lds + 8192, pf, blockIdx.x, y, 0); return; }
    if (y == 9) { if (blockIdx.x < 64) pool_body(lds, blockIdx.x, pf.A, aw, mw, cw); return; }
    int flat = (y - 10) * 128 + blockIdx.x;   // 0..511
    gemm_body<64, 64, 0, EPI_NEGCW>(lds, lds + 4096, ph, flat & 3, (flat >> 2) & 1, flat >> 3);
}

// q-only GEMM (y<2, 64^2) ∥ poolcw (y==2) ∥ Htn_{prev} (y in 3..4)
__global__ __launch_bounds__(256) void k_qpool_htn(GemmP pq, GemmP ph,
                                                   const float* aw, const float* mw,
                                                   float* cw) {
    __shared__ __align__(16) ushort_t lds[2 * 64 * 64];
    int y = blockIdx.y;
    if (y < 2) { gemm_body<64, 64, 0, EPI_RELU>(lds, lds + 4096, pq, blockIdx.x, y, 0); return; }
    if (y == 2) { if (blockIdx.x < 64) pool_body(lds, blockIdx.x, pq.A, aw, mw, cw); return; }
    int flat = (y - 3) * 256 + blockIdx.x;    // 0..511
    gemm_body<64, 64, 0, EPI_NEGCW>(lds, lds + 4096, ph, flat & 3, (flat >> 2) & 1, flat >> 3);
}

// sigxg (z<128) ∥ Y_{prev} (z in 128..191)
__global__ __launch_bounds__(256) void k_sigxg_y(GemmP ps, GemmP px, GemmP py) {
    __shared__ __align__(16) ushort_t aT[64 * 64];
    __shared__ __align__(16) ushort_t bT[64 * 64];
    int z = blockIdx.z;
    if (z < 64)       gemm_body<64, 64, 3, EPI_SIG>(aT, bT, ps, blockIdx.x, blockIdx.y, z);
    else if (z < 128) gemm_body<64, 64, 0, EPI_XG>(aT, bT, px, blockIdx.x, blockIdx.y, z - 64);
    else              gemm_body<64, 64, 2, EPI_Y>(aT, bT, py, blockIdx.x, blockIdx.y, z - 128);
}

// ---------------- small kernels ----------------

// combine body: 5 bf16 split-K partials + bias -> bf16 fbuf (x8 elems/thread)
__device__ __forceinline__ void combine_body(int bid, const ushort_t* t,
                                             const float* fbias_s, ushort_t* f) {
    int idx = bid * 256 + threadIdx.x;
    const long long N = 16384ll * 256;
    ushort8 a0 = *(const ushort8*)(t + (long long)idx * 8);
    ushort8 a1 = *(const ushort8*)(t + N + (long long)idx * 8);
    ushort8 a2 = *(const ushort8*)(t + 2 * N + (long long)idx * 8);
    ushort8 a3 = *(const ushort8*)(t + 3 * N + (long long)idx * 8);
    ushort8 a4 = *(const ushort8*)(t + 4 * N + (long long)idx * 8);
    int cb = (idx * 8) & 255;
    ushort8 o;
#pragma unroll
    for (int k = 0; k < 8; ++k)
        o[k] = f2b(b2f(a0[k]) + b2f(a1[k]) + b2f(a2[k]) + b2f(a3[k]) + b2f(a4[k]) + fbias_s[cb + k]);
    *(ushort8*)&f[(long long)idx * 8] = o;
}

__global__ void k_combine(const ushort_t* __restrict__ t, const float* __restrict__ fbias_s,
                          ushort_t* __restrict__ f) {
    combine_body(blockIdx.x, t, fbias_s, f);
}

// combine_{s+1} (blocks < 2048) ∥ pscale_s (blocks 2048..2175) — both ready
// after the BIG_{s+1}||sigxg_s dispatch; independent buffers.
__global__ __launch_bounds__(256) void k_comb_ps(const ushort_t* __restrict__ t,
                                                 const float* __restrict__ fbias_s,
                                                 ushort_t* __restrict__ f,
                                                 const ushort_t* __restrict__ q,
                                                 const float* __restrict__ dsum8,
                                                 float* __restrict__ dscale,
                                                 ushort_t* __restrict__ Pt) {
    int bid = blockIdx.x;
    if (bid < 2048) { combine_body(bid, t, fbias_s, f); return; }
    int pb = bid - 2048;                 // 0..127
    pscale_body(pb & 1, pb >> 1, q, dsum8, dscale, Pt);
}

// x_sum = x_cur * (1 + bilinear_up2x_align_corners(x_lat)); bf16 [B*256][1024]
__global__ void k_upsum(const float* __restrict__ xc, const float* __restrict__ xl,
                        ushort_t* __restrict__ xs) {
    __shared__ float lat[64 * 64];
    __shared__ ushort_t tile[64 * 258];
    int b = blockIdx.x, c0 = blockIdx.y * 64;
    int t = threadIdx.x;
    for (int i = t; i < 4096; i += 256)
        lat[i] = xl[((long long)(b * 1024 + c0 + (i >> 6))) * 64 + (i & 63)];
    __syncthreads();
    int y = t >> 4, x = t & 15;
    float fy = y * (7.f / 15.f); int y0 = (int)fy; float wy = fy - y0; int y1 = y0 + 1 > 7 ? 7 : y0 + 1;
    float fx = x * (7.f / 15.f); int x0 = (int)fx; float wx = fx - x0; int x1 = x0 + 1 > 7 ? 7 : x0 + 1;
    for (int cc = 0; cc < 64; ++cc) {
        float cur = xc[((long long)(b * 1024 + c0 + cc)) * 256 + t];
        const float* L = &lat[cc * 64];
        float tv = L[y0 * 8 + x0] * (1.f - wx) + L[y0 * 8 + x1] * wx;
        float bv = L[y1 * 8 + x0] * (1.f - wx) + L[y1 * 8 + x1] * wx;
        float up = tv + (bv - tv) * wy;
        tile[cc * 258 + t] = f2b(cur * (1.f + up));
    }
    __syncthreads();
    for (int i = t; i < 16384; i += 256) {
        int px = i >> 6, cc = i & 63;
        xs[((long long)(b * 256 + px)) * 1024 + c0 + cc] = tile[cc * 258 + px];
    }
}

__global__ void k_pscale(const ushort_t* __restrict__ q, const float* __restrict__ dsum8,
                         float* __restrict__ dscale, ushort_t* __restrict__ Pt) {
    pscale_body(blockIdx.x, blockIdx.y, q, dsum8, dscale, Pt);
}

// One-shot weight/bias packing (r10 layout)
__global__ void k_packall(const float* r0, const float* r1, const float* r2,
                          const float* convw, const float* c1w, const float* c3w,
                          const float* ckw, const float* gcnw,
                          const float* rb0, const float* rb1, const float* rb2,
                          const float* cb, const float* c1b, const float* ckbias,
                          ushort_t* wbig3, ushort_t* wfq, ushort_t* w3b,
                          ushort_t* gcnT, float* fqbias, float* fbias,
                          ushort_t* zpage) {
    int blk = blockIdx.x, tid = threadIdx.x;
    if (blk < 768) {
        __shared__ float lw[10240];
        int s = blk >> 8, o = blk & 255;
        const float* rate = s == 0 ? r0 : (s == 1 ? r1 : r2);
        for (int i = tid; i < 9216; i += 256) lw[i] = rate[(long long)o * 9216 + i];
        for (int i = tid; i < 1024; i += 256) lw[9216 + i] = convw[(long long)o * 1024 + i];
        __syncthreads();
        ushort_t* dst = wbig3 + (long long)blk * 10240;
        for (int i = tid; i < 10240; i += 256) {
            int tap = i >> 10, ci = i & 1023;
            float v = (tap < 9) ? lw[ci * 9 + tap] : lw[9216 + ci];
            dst[i] = f2b(v);
        }
        return;
    }
    const int R1 = 262144;            // wfq: conv1_w part
    const int R2 = R1 + 32768;        // wfq: ck_w part
    const int R3 = R2 + 786432;       // w3b
    const int R4 = R3 + 65536;        // gcnT
    const int R5 = R4 + 1152;         // fqbias
    const int R6 = R5 + 768;          // fbias
    const int R7 = R6 + 4096;         // zpage
    int base = (blk - 768) * 2048 + tid * 8;
#pragma unroll
    for (int k = 0; k < 8; ++k) {
        int i = base + k;
        if (i >= R7) return;
        if (i < R1) wfq[i] = f2b(c1w[i]);
        else if (i < R2) wfq[i] = f2b(ckw[i - R1]);
        else if (i < R3) w3b[i - R2] = f2b(c3w[i - R2]);
        else if (i < R4) {
            int ii = i - R3; int c2 = ii >> 8, c1 = ii & 255;
            gcnT[ii] = f2b(gcnw[c1 * 256 + c2]);
        } else if (i < R5) {
            int ii = i - R4;
            fqbias[ii] = (ii < 1024) ? c1b[ii] : ckbias[ii - 1024];
        } else if (i < R6) {
            int ii = i - R5; int s = ii >> 8, t = ii & 255;
            const float* rb = s == 0 ? rb0 : (s == 1 ? rb1 : rb2);
            fbias[ii] = rb[t] + cb[t];
        } else {
            zpage[i - R6] = 0;
        }
    }
}

__global__ void k_sentinel(float* o, int n, float v) {
    int i = blockIdx.x * 256 + threadIdx.x; if (i < n) o[i] = v;
}

// ---------------- launch ----------------
extern "C" void kernel_launch(void* const* d_in, const int* in_sizes, int n_in,
                              void* d_out, int out_size, void* d_ws, size_t ws_size,
                              hipStream_t stream) {
    const float* x_cur  = (const float*)d_in[0];
    const float* x_lat  = (const float*)d_in[1];
    const float* conv_w = (const float*)d_in[2];
    const float* conv_b = (const float*)d_in[3];
    const float* conv1_w = (const float*)d_in[4];
    const float* conv1_b = (const float*)d_in[5];
    const float* conv3_w = (const float*)d_in[6];
    const float* conv3_b = (const float*)d_in[7];
    const float* rate_w[3] = {(const float*)d_in[8], (const float*)d_in[10], (const float*)d_in[12]};
    const float* rate_b[3] = {(const float*)d_in[9], (const float*)d_in[11], (const float*)d_in[13]};
    const float* ck_w  = (const float*)d_in[14];
    const float* ck_b  = (const float*)d_in[15];
    const float* avg_w = (const float*)d_in[16];
    const float* max_w = (const float*)d_in[17];
    const float* gcn_w = (const float*)d_in[18];
    float* out = (float*)d_out;

    char* w = (char*)d_ws;
    auto take = [&](size_t bytes) { void* p = (void*)w; w += (bytes + 255) & ~(size_t)255; return p; };
    ushort_t* xsum   = (ushort_t*)take(16384ll * 1024 * 2);    // 33.55MB
    ushort_t* feat   = (ushort_t*)take(16384ll * 1024 * 2);    // 33.55MB
    ushort_t* fbufP[2];                                        // stage-parity
    fbufP[0] = (ushort_t*)take(16384ll * 256 * 2);             // 8.39MB
    fbufP[1] = (ushort_t*)take(16384ll * 256 * 2);             // 8.39MB
    ushort_t* qbufP[2];
    qbufP[0] = (ushort_t*)take(16384ll * 128 * 2);             // 4.19MB
    qbufP[1] = (ushort_t*)take(16384ll * 128 * 2);             // 4.19MB
    ushort_t* xgt    = (ushort_t*)take(64ll * 256 * 256 * 2);  // 8.39MB
    ushort_t* Pt     = (ushort_t*)take(64ll * 128 * 256 * 2);  // 4.19MB
    ushort_t* Htn    = (ushort_t*)take(64ll * 256 * 128 * 2);  // 4.19MB
    ushort_t* wbig3  = (ushort_t*)take(3ll * 256 * 10240 * 2); // 15.73MB
    ushort_t* wfq    = (ushort_t*)take(1152ll * 256 * 2);
    ushort_t* w3b    = (ushort_t*)take(1024ll * 768 * 2);
    ushort_t* gcnT   = (ushort_t*)take(256ll * 256 * 2);
    ushort_t* zpage  = (ushort_t*)take(8192);
    float*    fqbias = (float*)take(1152 * 4);
    float*    fbias  = (float*)take(3 * 256 * 4);
    float*    cwbP[2];
    cwbP[0] = (float*)take(64 * 128 * 4);
    cwbP[1] = (float*)take(64 * 128 * 4);
    float*    dscale = (float*)take(64 * 256 * 4);
    float*    dsum8  = (float*)take(8ll * 64 * 256 * 4);
    ushort_t* catb   = (ushort_t*)take(16384ll * 768 * 2);     // 25.17MB
    ushort_t* ftmp   = (ushort_t*)take(5ll * 16384 * 256 * 2); // 41.94MB
    size_t need = (size_t)(w - (char*)d_ws);                   // ~195MB (<=204 proven)

    if (need > ws_size) {
        float v = 1.0e6f + (float)(ws_size >> 20);
        k_sentinel<<<(out_size + 255) / 256, 256, 0, stream>>>(out, out_size, v);
        return;
    }

    // per-stage GemmP builders
    auto PBIG = [&](int s) {
        GemmP p{};
        p.A = (s == 0) ? xsum : feat;
        p.B = wbig3 + (long long)s * 256 * 10240; p.ldb = 10240;
        p.Ksub = 2048; p.kSplit = 2048; p.dil = 1 << s;
        p.obf = ftmp; p.oBatch = 16384ll * 256;
        p.zpage = zpage;
        return p;
    };
    auto PSIG = [&](int s) {
        GemmP p{};
        p.A = qbufP[s & 1]; p.aBatch = 32768; p.lda = 128;
        p.B = qbufP[s & 1]; p.bBatch = 32768; p.ldb = 128;
        p.Ksub = 128; p.dsum = dsum8; p.cw = cwbP[s & 1];
        return p;
    };
    auto PXG = [&](int s) {
        GemmP p{};
        p.A = gcnT; p.aBatch = 0;            p.lda = 256;
        p.B = fbufP[s & 1]; p.bBatch = 65536; p.ldb = 256;
        p.Ksub = 256;
        p.obf = xgt; p.oBatch = 65536; p.ldo = 256;
        return p;
    };
    auto PHTN = [&](int s) {
        GemmP p{};
        p.A = xgt; p.aBatch = 65536; p.lda = 256;
        p.B = Pt;  p.bBatch = 32768; p.ldb = 256;
        p.Ksub = 256; p.cw = cwbP[s & 1];
        p.obf = Htn; p.oBatch = 32768; p.ldo = 128;
        return p;
    };
    auto PY = [&](int s) {
        GemmP p{};
        p.A = fbufP[s & 1]; p.aBatch = 65536; p.lda = 256;
        p.B = gcnT; p.bBatch = 0;             p.ldb = 256;
        p.A2 = qbufP[s & 1]; p.a2Batch = 32768; p.lda2 = 128; p.rscale = dscale;
        p.B2 = Htn;          p.b2Batch = 32768; p.ldb2 = 128;
        p.Ksub = 384;
        p.res = fbufP[s & 1]; p.resBatch = 65536; p.ldres = 256;
        p.obf = catb + s * 256; p.oBatch = 256ll * 768; p.ldo = 768;
        return p;
    };
    auto PFQ = [&](int s) {
        GemmP p{};
        p.A = fbufP[s & 1]; p.lda = 256; p.B = wfq; p.ldb = 256;
        p.Ksub = 256; p.bias = fqbias;
        p.res = xsum;
        p.obf = feat; p.obf2 = qbufP[s & 1];
        return p;
    };
    GemmP pz{};  // dummy for unused roles

    k_packall<<<768 + 563, 256, 0, stream>>>(
        rate_w[0], rate_w[1], rate_w[2], conv_w, conv1_w, conv3_w, ck_w, gcn_w,
        rate_b[0], rate_b[1], rate_b[2], conv_b, conv1_b, ck_b,
        wbig3, wfq, w3b, gcnT, fqbias, fbias, zpage);
    k_upsum<<<dim3(64, 16), 256, 0, stream>>>(x_cur, x_lat, xsum);

    // ---- software-pipelined schedule: stage-s GR tail rides inside stage-
    // (s+1) dispatches; combine_{s+1} || pscale_s fused (both ready after
    // BIG_{s+1}||sigxg_s; disjoint buffers) ----
    // 1: BIG_0
    k_big_sig_y<<<dim3(128, 2, 5), 256, 0, stream>>>(PBIG(0), pz, pz, pz);
    // 2: combine_0
    k_combine<<<2048, 256, 0, stream>>>(ftmp, fbias + 0 * 256, fbufP[0]);
    // 3: FQ_0 + pool_0
    k_fqpool_htn<<<dim3(128, 10), 256, 0, stream>>>(PFQ(0), pz, avg_w, max_w, cwbP[0]);
    // 4: BIG_1 || sigxg_0
    k_big_sig_y<<<dim3(128, 2, 13), 256, 0, stream>>>(PBIG(1), PSIG(0), PXG(0), pz);
    // 5: combine_1 || pscale_0
    k_comb_ps<<<2048 + 128, 256, 0, stream>>>(ftmp, fbias + 1 * 256, fbufP[1],
                                              qbufP[0], dsum8, dscale, Pt);
    // 6: FQ_1 + pool_1 || Htn_0
    k_fqpool_htn<<<dim3(128, 14), 256, 0, stream>>>(PFQ(1), PHTN(0), avg_w, max_w, cwbP[1]);
    // 7: BIG_2 || sigxg_1 || Y_0
    k_big_sig_y<<<dim3(128, 2, 17), 256, 0, stream>>>(PBIG(2), PSIG(1), PXG(1), PY(0));
    // 8: combine_2 || pscale_1
    k_comb_ps<<<2048 + 128, 256, 0, stream>>>(ftmp, fbias + 2 * 256, fbufP[0],
                                              qbufP[1], dsum8, dscale, Pt);
    // 9: q_2 + pool_2 || Htn_1
    {
        GemmP pq{};
        pq.A = fbufP[0]; pq.lda = 256; pq.B = wfq + 1024 * 256; pq.ldb = 256;
        pq.Ksub = 256;
        pq.bias = ck_b; pq.obf = qbufP[0]; pq.ldo = 128;
        k_qpool_htn<<<dim3(256, 5), 256, 0, stream>>>(pq, PHTN(1), avg_w, max_w, cwbP[0]);
    }
    // 10: sigxg_2 || Y_1
    k_sigxg_y<<<dim3(4, 4, 192), 256, 0, stream>>>(PSIG(2), PXG(2), PY(1));
    // 11: pscale_2
    k_pscale<<<dim3(2, 64), 256, 0, stream>>>(qbufP[0], dsum8, dscale, Pt);
    // 12: Htn_2
    gemm_k<64, 64, 0, EPI_NEGCW><<<dim3(4, 2, 64), 256, 0, stream>>>(PHTN(2));
    // 13: Y_2
    gemm_k<64, 64, 2, EPI_Y><<<dim3(4, 4, 64), 256, 0, stream>>>(PY(2));
    // 14: OUT = cat @ w3^T + b — 128x128 tiles (2x MFMA density vs 64x128)
    {
        GemmP p{};
        p.A = w3b;  p.lda = 768;
        p.B = catb; p.ldb = 768;
        p.Ksub = 768; p.bias = conv3_b; p.of32 = out;
        gemm_k<128, 128, 0, EPI_OUTT><<<dim3(8, 128, 1), 256, 0, stream>>>(p);
    }
}

// Round 18
// 622.056 us; speedup vs baseline: 1.0128x; 1.0128x over previous
//
#include <hip/hip_runtime.h>

// r15 LESSON: in-kernel split-K combine (atomic + __threadfence) REGRESSED
// 626 -> 1280 us (device-scope fence = L2 thrash on 8-XCD gfx950).
// r11 LESSON: 256^2 coarse counted-vmcnt BIG regressed (lost 5-blocks/CU
// cross-block overlap). Keep: 128^2 BIG + separate-dispatch reduction.
// r17: combine||pscale merge + OUT 128^2 = neutral (kept; fewer dispatches).
// r18: + T5 setprio around BIG MFMA (merged dispatches have wave role
// diversity = T5's regime) + packall||upsum prologue merge.

typedef unsigned short ushort_t;
typedef unsigned int uint32;
typedef __attribute__((ext_vector_type(8))) unsigned short ushort8;
typedef __attribute__((ext_vector_type(8))) __bf16 bf16x8;
typedef __attribute__((ext_vector_type(4))) float f32x4;

__device__ __forceinline__ ushort_t f2b(float f) {
    union { float f; uint32 u; } v; v.f = f;
    uint32 r = v.u + 0x7fffu + ((v.u >> 16) & 1u);
    return (ushort_t)(r >> 16);
}
__device__ __forceinline__ float b2f(ushort_t b) {
    union { uint32 u; float f; } v; v.u = ((uint32)b) << 16;
    return v.f;
}
__device__ __forceinline__ float sigm(float x) { return 1.f / (1.f + __expf(-x)); }

__device__ __forceinline__ void gload_lds16(const void* g, void* l) {
    __builtin_amdgcn_global_load_lds(
        (__attribute__((address_space(1))) void*)g,
        (__attribute__((address_space(3))) void*)l, 16, 0, 0);
}

// epilogues
constexpr int EPI_RELU  = 1;  // bf16 relu(acc+bias) -> obf (q for s==2)
constexpr int EPI_FQ    = 2;  // merged: col<1024 feat=acc+bias+res; col>=1024 q=relu(acc+bias)
constexpr int EPI_SIG   = 3;  // rowsum sigmoid(acc) -> dsum[(by*2+wc)][z*256+row]
constexpr int EPI_XG    = 4;  // bf16 acc -> obf[z*oB + row*ldo + col]  (XGt)
constexpr int EPI_NEGCW = 5;  // bf16 -acc*cw[z*128+col] -> obf (Htn)
constexpr int EPI_Y     = 6;  // bf16 res + acc -> obf (catb slice)
constexpr int EPI_OUTT  = 7;  // fp32 acc+bias[row]; row=outchan, col=pixel -> NCHW coalesced

struct GemmP {
    const ushort_t* A; const ushort_t* B;
    const ushort_t* A2; const ushort_t* B2;     // AMODE==2 second source (gk >= 256)
    long long aBatch, bBatch, a2Batch, b2Batch;
    int lda, ldb, lda2, ldb2;
    int Ksub, kSplit, dil;
    const float* bias;
    const ushort_t* res; long long resBatch; int ldres;
    ushort_t* obf; long long oBatch; int ldo;
    ushort_t* obf2;
    float* of32;
    const float* cw;
    const float* rscale;   // AMODE==2: per-row scale of A2 (d factor)
    float* dsum;
    const ushort_t* zpage;
};

// ---------------------------------------------------------------------------
// BIG implicit-GEMM body (9 dilated conv taps + conv1x1 identity tap),
// m97-style global_load_lds staging, split-K=5, 128x128 tile, BK=64.
// LDS image S[r][g] = G[r][g ^ (r&7)] via pre-swizzled per-lane source;
// reads apply the same XOR (conflict-free, r3-verified). Tap-aligned split-K
// chunks (2048 = 2 taps): tap geometry hoisted to per-tap outer loop. OOB
// rows use an 8KB zero page. bf16 partials. T5 setprio wraps the MFMA
// cluster (merged dispatches have heterogeneous co-resident blocks).
// ---------------------------------------------------------------------------
__device__ __forceinline__ void big_body(ushort_t* aT, ushort_t* bT,
                                         const GemmP& p, int bx, int by, int z) {
    const int tid = threadIdx.x;
    const int m0 = bx * 128, n0 = by * 128;
    const int lane = tid & 63, wid = tid >> 6;
    const int l15 = lane & 15, l16 = lane >> 4;
    const int wr = wid >> 1, wc = wid & 1;
    const int lrow = lane >> 3;
    const int sgran = (lane & 7) ^ lrow;

    int ayy[4], axx[4];
    const ushort_t* aBase[4];
    const ushort_t* bBase[4];
#pragma unroll
    for (int i = 0; i < 4; ++i) {
        int row = wid * 32 + i * 8 + lrow;
        int m = m0 + row;
        int bb = m >> 8;
        ayy[i] = (m >> 4) & 15; axx[i] = m & 15;
        aBase[i] = p.A + (long long)bb * 262144 + sgran * 8;
        bBase[i] = p.B + (long long)(n0 + row) * p.ldb + sgran * 8;
    }

    f32x4 acc[4][4];
#pragma unroll
    for (int i = 0; i < 4; ++i)
#pragma unroll
        for (int j = 0; j < 4; ++j) acc[i][j] = (f32x4){0.f, 0.f, 0.f, 0.f};

    const int gk0 = z * p.kSplit;          // tap-aligned
    const int ntap = p.Ksub >> 10;
    for (int ti = 0; ti < ntap; ++ti) {
        const int tap = (gk0 >> 10) + ti;
        int dy = 0, dx = 0;
        if (tap < 9) { int ky = tap / 3; dy = (ky - 1) * p.dil; dx = (tap - ky * 3 - 1) * p.dil; }
        const ushort_t* gaA[4];
        const ushort_t* gaB[4];
#pragma unroll
        for (int i = 0; i < 4; ++i) {
            int iy = ayy[i] + dy, ix = axx[i] + dx;
            bool ok = ((unsigned)iy < 16u) && ((unsigned)ix < 16u);
            gaA[i] = ok ? (aBase[i] + (((iy << 4) + ix) << 10)) : (p.zpage + sgran * 8);
            gaB[i] = bBase[i] + (tap << 10);
        }
        for (int kk = 0; kk < 16; ++kk) {
            const int kin = kk << 6;
#pragma unroll
            for (int i = 0; i < 4; ++i)
                gload_lds16(gaA[i] + kin, &aT[(wid * 32 + i * 8) * 64]);
#pragma unroll
            for (int i = 0; i < 4; ++i)
                gload_lds16(gaB[i] + kin, &bT[(wid * 32 + i * 8) * 64]);
            asm volatile("s_waitcnt vmcnt(0)" ::: "memory");
            __syncthreads();
#pragma unroll
            for (int ks = 0; ks < 2; ++ks) {
                bf16x8 af[4], bfr[4];
#pragma unroll
                for (int mi = 0; mi < 4; ++mi) {
                    int rr = wr * 64 + mi * 16 + l15;
                    int cc = (ks * 32 + l16 * 8) ^ ((rr & 7) << 3);
                    af[mi] = __builtin_bit_cast(bf16x8, *(const ushort8*)&aT[rr * 64 + cc]);
                }
#pragma unroll
                for (int ni = 0; ni < 4; ++ni) {
                    int rr = wc * 64 + ni * 16 + l15;
                    int cc = (ks * 32 + l16 * 8) ^ ((rr & 7) << 3);
                    bfr[ni] = __builtin_bit_cast(bf16x8, *(const ushort8*)&bT[rr * 64 + cc]);
                }
                __builtin_amdgcn_s_setprio(1);   // T5: favor MFMA-entering waves
#pragma unroll
                for (int mi = 0; mi < 4; ++mi)
#pragma unroll
                    for (int ni = 0; ni < 4; ++ni)
                        acc[mi][ni] = __builtin_amdgcn_mfma_f32_16x16x32_bf16(af[mi], bfr[ni], acc[mi][ni], 0, 0, 0);
                __builtin_amdgcn_s_setprio(0);
            }
            __syncthreads();
        }
    }
#pragma unroll
    for (int mi = 0; mi < 4; ++mi)
#pragma unroll
        for (int ni = 0; ni < 4; ++ni) {
            int gcol = n0 + wc * 64 + ni * 16 + l15;
            int growb = m0 + wr * 64 + mi * 16 + l16 * 4;
#pragma unroll
            for (int r = 0; r < 4; ++r)
                p.obf[(long long)z * p.oBatch + (long long)(growb + r) * 256 + gcol] =
                    f2b(acc[mi][ni][r]);
        }
}

// ---------------------------------------------------------------------------
// Generic 4-wave MFMA GEMM body (explicit bx/by/z so merged kernels can
// remap grid planes to roles): C = A.B^T, bf16 in, fp32 acc.
// AMODE==0: single source. AMODE==2: dual source. AMODE==3: A K-scaled by cw.
// ---------------------------------------------------------------------------
template<int BM, int BN, int AMODE, int EPI>
__device__ __forceinline__ void gemm_body(ushort_t* aT, ushort_t* bT,
                                          const GemmP& p, int bx, int by, int z) {
    constexpr int APASS = BM / 32, BPASS = BN / 32;
    constexpr int MFRAG = BM / 32, NFRAG = BN / 32;
    const int tid = threadIdx.x;
    const int m0 = bx * BM, n0 = by * BN;
    const int lane = tid & 63, wid = tid >> 6;
    const int l15 = lane & 15, l16 = lane >> 4;
    const int wr = wid >> 1, wc = wid & 1;
    const int srow = tid >> 3, scol = (tid & 7) * 8;
    const int swcol = scol ^ ((srow & 7) << 3);

    const ushort_t* aptr[APASS];
    const ushort_t* bptr[BPASS];
    const ushort_t* aptr2[APASS];
    const ushort_t* bptr2[BPASS];
    float rsA[APASS];
#pragma unroll
    for (int pi = 0; pi < APASS; ++pi)
        aptr[pi] = p.A + (long long)z * p.aBatch +
                   (long long)(m0 + pi * 32 + srow) * p.lda + scol;
#pragma unroll
    for (int pi = 0; pi < BPASS; ++pi)
        bptr[pi] = p.B + (long long)z * p.bBatch +
                   (long long)(n0 + pi * 32 + srow) * p.ldb + scol;
    if constexpr (AMODE == 2) {
#pragma unroll
        for (int pi = 0; pi < APASS; ++pi) {
            aptr2[pi] = p.A2 + (long long)z * p.a2Batch +
                        (long long)(m0 + pi * 32 + srow) * p.lda2 + scol;
            rsA[pi] = p.rscale[z * 256 + m0 + pi * 32 + srow];
        }
#pragma unroll
        for (int pi = 0; pi < BPASS; ++pi)
            bptr2[pi] = p.B2 + (long long)z * p.b2Batch +
                        (long long)(n0 + pi * 32 + srow) * p.ldb2 + scol;
    }

    f32x4 acc[MFRAG][NFRAG];
#pragma unroll
    for (int i = 0; i < MFRAG; ++i)
#pragma unroll
        for (int j = 0; j < NFRAG; ++j) acc[i][j] = (f32x4){0.f, 0.f, 0.f, 0.f};

    ushort8 ar[APASS], br[BPASS];
    auto ldg = [&](int gk) {
        if (AMODE == 2 && gk >= 256) {
            int g2 = gk - 256;
#pragma unroll
            for (int pi = 0; pi < APASS; ++pi) {
                ushort8 t8 = *(const ushort8*)(aptr2[pi] + g2);
#pragma unroll
                for (int k = 0; k < 8; ++k) t8[k] = f2b(b2f(t8[k]) * rsA[pi]);
                ar[pi] = t8;
            }
#pragma unroll
            for (int pi = 0; pi < BPASS; ++pi) br[pi] = *(const ushort8*)(bptr2[pi] + g2);
        } else if constexpr (AMODE == 3) {
#pragma unroll
            for (int pi = 0; pi < APASS; ++pi) {
                ushort8 t8 = *(const ushort8*)(aptr[pi] + gk);
#pragma unroll
                for (int k = 0; k < 8; ++k)
                    t8[k] = f2b(b2f(t8[k]) * p.cw[(z << 7) + gk + scol + k]);
                ar[pi] = t8;
            }
#pragma unroll
            for (int pi = 0; pi < BPASS; ++pi) br[pi] = *(const ushort8*)(bptr[pi] + gk);
        } else {
#pragma unroll
            for (int pi = 0; pi < APASS; ++pi) ar[pi] = *(const ushort8*)(aptr[pi] + gk);
#pragma unroll
            for (int pi = 0; pi < BPASS; ++pi) br[pi] = *(const ushort8*)(bptr[pi] + gk);
        }
    };

    const int gk0 = z * p.kSplit;
    ldg(gk0);
    const int iters = p.Ksub >> 6;
    for (int it = 0; it < iters; ++it) {
#pragma unroll
        for (int pi = 0; pi < APASS; ++pi)
            *(ushort8*)&aT[(pi * 32 + srow) * 64 + swcol] = ar[pi];
#pragma unroll
        for (int pi = 0; pi < BPASS; ++pi)
            *(ushort8*)&bT[(pi * 32 + srow) * 64 + swcol] = br[pi];
        __syncthreads();
        if (it + 1 < iters) ldg(gk0 + (it + 1) * 64);
#pragma unroll
        for (int ks = 0; ks < 2; ++ks) {
            bf16x8 af[MFRAG], bfr[NFRAG];
#pragma unroll
            for (int mi = 0; mi < MFRAG; ++mi) {
                int rr = wr * (BM / 2) + mi * 16 + l15;
                int cc = (ks * 32 + l16 * 8) ^ ((rr & 7) << 3);
                af[mi] = __builtin_bit_cast(bf16x8, *(const ushort8*)&aT[rr * 64 + cc]);
            }
#pragma unroll
            for (int ni = 0; ni < NFRAG; ++ni) {
                int rr = wc * (BN / 2) + ni * 16 + l15;
                int cc = (ks * 32 + l16 * 8) ^ ((rr & 7) << 3);
                bfr[ni] = __builtin_bit_cast(bf16x8, *(const ushort8*)&bT[rr * 64 + cc]);
            }
#pragma unroll
            for (int mi = 0; mi < MFRAG; ++mi)
#pragma unroll
                for (int ni = 0; ni < NFRAG; ++ni)
                    acc[mi][ni] = __builtin_amdgcn_mfma_f32_16x16x32_bf16(af[mi], bfr[ni], acc[mi][ni], 0, 0, 0);
        }
        __syncthreads();
    }

    // ---------------- epilogue ----------------
#pragma unroll
    for (int mi = 0; mi < MFRAG; ++mi) {
        if constexpr (EPI == EPI_SIG) {
#pragma unroll
            for (int r = 0; r < 4; ++r) {
                float sv = 0.f;
#pragma unroll
                for (int ni = 0; ni < NFRAG; ++ni) sv += sigm(acc[mi][ni][r]);
                sv += __shfl_xor(sv, 1); sv += __shfl_xor(sv, 2);
                sv += __shfl_xor(sv, 4); sv += __shfl_xor(sv, 8);
                if (l15 == 0) {
                    int grow = m0 + wr * (BM / 2) + mi * 16 + l16 * 4 + r;
                    int q8 = by * 2 + wc;  // disjoint slot -> deterministic
                    p.dsum[q8 * 16384 + z * 256 + grow] = sv;
                }
            }
        } else {
#pragma unroll
            for (int ni = 0; ni < NFRAG; ++ni) {
                int gcol = n0 + wc * (BN / 2) + ni * 16 + l15;
                int growb = m0 + wr * (BM / 2) + mi * 16 + l16 * 4;
#pragma unroll
                for (int r = 0; r < 4; ++r) {
                    int grow = growb + r;
                    float v = acc[mi][ni][r];
                    if constexpr (EPI == EPI_RELU) {
                        v += p.bias[gcol]; v = fmaxf(v, 0.f);
                        p.obf[(long long)grow * p.ldo + gcol] = f2b(v);
                    } else if constexpr (EPI == EPI_FQ) {
                        v += p.bias[gcol];
                        if (gcol < 1024) {   // uniform per tile (1024%BN==0)
                            v += b2f(p.res[(long long)grow * 1024 + gcol]);
                            p.obf[(long long)grow * 1024 + gcol] = f2b(v);
                        } else {
                            v = fmaxf(v, 0.f);
                            p.obf2[(long long)grow * 128 + (gcol - 1024)] = f2b(v);
                        }
                    } else if constexpr (EPI == EPI_XG) {
                        p.obf[(long long)z * p.oBatch + (long long)grow * p.ldo + gcol] = f2b(v);
                    } else if constexpr (EPI == EPI_NEGCW) {
                        v *= -p.cw[z * 128 + gcol];
                        p.obf[(long long)z * p.oBatch + (long long)grow * p.ldo + gcol] = f2b(v);
                    } else if constexpr (EPI == EPI_Y) {
                        v = b2f(p.res[(long long)z * p.resBatch + (long long)grow * p.ldres + gcol]) + v;
                        p.obf[(long long)z * p.oBatch + (long long)grow * p.ldo + gcol] = f2b(v);
                    } else if constexpr (EPI == EPI_OUTT) {
                        v += p.bias[grow];               // row = out-channel
                        int bb = gcol >> 8, px = gcol & 255;
                        p.of32[((long long)bb * 1024 + grow) * 256 + px] = v;  // coalesced over px
                    }
                }
            }
        }
    }
}

template<int BM, int BN, int AMODE, int EPI>
__global__ __launch_bounds__(256) void gemm_k(GemmP p) {
    __shared__ __align__(16) ushort_t aT[BM * 64];
    __shared__ __align__(16) ushort_t bT[BN * 64];
    gemm_body<BM, BN, AMODE, EPI>(aT, bT, p, blockIdx.x, blockIdx.y, blockIdx.z);
}

// avg/max pool + channel-weight MLP body (256 threads; LDS reused)
__device__ __forceinline__ void pool_body(void* lds, int b, const ushort_t* f,
                                          const float* aw, const float* mw,
                                          float* cw) {
    float* sa = (float*)lds;
    float* sm = sa + 256;
    int t = threadIdx.x;
    float s = 0.f, m = -3.4e38f;
    const ushort_t* base = f + (long long)b * 65536 + t;
    for (int px = 0; px < 256; ++px) { float v = b2f(base[px * 256]); s += v; m = fmaxf(m, v); }
    sa[t] = s * (1.f / 256.f);
    sm[t] = m;
    __syncthreads();
    if (t < 128) {
        float s1 = 0.f, s2 = 0.f;
        const float* a = aw + t * 256; const float* w = mw + t * 256;
        for (int c = 0; c < 256; ++c) { s1 += sa[c] * a[c]; s2 += sm[c] * w[c]; }
        s1 = fmaxf(s1, 0.f); s2 = fmaxf(s2, 0.f);
        cw[b * 128 + t] = sigm(s1 + s2);
    }
}

// pscale body: d = rsqrt(sum of 8 dsum slots); dscale (f32) + transposed Pt
__device__ __forceinline__ void pscale_body(int jh, int b,
                                            const ushort_t* q, const float* dsum8,
                                            float* dscale, ushort_t* Pt) {
    __shared__ ushort_t t[128][130];
    __shared__ float dd[128];
    int j0 = jh * 128;
    int tid = threadIdx.x;
    if (tid < 128) {
        int pix = b * 256 + j0 + tid;
        float s = 0.f;
#pragma unroll
        for (int qs = 0; qs < 8; ++qs) s += dsum8[qs * 16384 + pix];
        float r = rsqrtf(s);
        dd[tid] = r;
        dscale[pix] = r;
    }
    __syncthreads();
    int jr = tid >> 7, m = tid & 127;
    for (int i = 0; i < 64; ++i) {
        int j = i * 2 + jr;
        long long qi = ((long long)(b * 256 + j0 + j)) * 128 + m;
        t[j][m] = f2b(dd[j] * b2f(q[qi]));
    }
    __syncthreads();
    for (int i = 0; i < 64; ++i) {
        int mm = i * 2 + jr;
        Pt[((long long)b << 15) + (mm << 8) + j0 + m] = t[m][mm];
    }
}

// BIG (z<5) ∥ sigxg_{prev} (z in 5..12) ∥ Y_{prev2} (z in 13..16).
__global__ __launch_bounds__(256) void k_big_sig_y(GemmP pb, GemmP ps, GemmP px,
                                                   GemmP py) {
    __shared__ __align__(16) ushort_t lds[2 * 128 * 64];
    int z = blockIdx.z;
    if (z < 5) { big_body(lds, lds + 8192, pb, blockIdx.x, blockIdx.y, z); return; }
    if (z < 13) {
        int flat = (z - 5) * 256 + blockIdx.y * 128 + blockIdx.x;  // 0..2047
        int bx = flat & 3, by = (flat >> 2) & 3, bz = flat >> 4;
        if (bz < 64) gemm_body<64, 64, 3, EPI_SIG>(lds, lds + 4096, ps, bx, by, bz);
        else         gemm_body<64, 64, 0, EPI_XG>(lds, lds + 4096, px, bx, by, bz - 64);
        return;
    }
    int flat = (z - 13) * 256 + blockIdx.y * 128 + blockIdx.x;     // 0..1023
    gemm_body<64, 64, 2, EPI_Y>(lds, lds + 4096, py, flat & 3, (flat >> 2) & 3, flat >> 4);
}

// FQ GEMM (y<9, 128^2) ∥ poolcw (y==9, x<64) ∥ Htn_{prev} (y in 10..13).
__global__ __launch_bounds__(256) void k_fqpool_htn(GemmP pf, GemmP ph,
                                                    const float* aw, const float* mw,
                                                    float* cw) {
    __shared__ __align__(16) ushort_t lds[2 * 128 * 64];
    int y = blockIdx.y;
    if (y < 9) { gemm_body<128, 128, 0, EPI_FQ>(lds, lds + 8192, pf, blockIdx.x, y, 0); return; }
    if (y == 9) { if (blockIdx.x < 64) pool_body(lds, blockIdx.x, pf.A, aw, mw, cw); return; }
    int flat = (y - 10) * 128 + blockIdx.x;   // 0..511
    gemm_body<64, 64, 0, EPI_NEGCW>(lds, lds + 4096, ph, flat & 3, (flat >> 2) & 1, flat >> 3);
}

// q-only GEMM (y<2, 64^2) ∥ poolcw (y==2) ∥ Htn_{prev} (y in 3..4)
__global__ __launch_bounds__(256) void k_qpool_htn(GemmP pq, GemmP ph,
                                                   const float* aw, const float* mw,
                                                   float* cw) {
    __shared__ __align__(16) ushort_t lds[2 * 64 * 64];
    int y = blockIdx.y;
    if (y < 2) { gemm_body<64, 64, 0, EPI_RELU>(lds, lds + 4096, pq, blockIdx.x, y, 0); return; }
    if (y == 2) { if (blockIdx.x < 64) pool_body(lds, blockIdx.x, pq.A, aw, mw, cw); return; }
    int flat = (y - 3) * 256 + blockIdx.x;    // 0..511
    gemm_body<64, 64, 0, EPI_NEGCW>(lds, lds + 4096, ph, flat & 3, (flat >> 2) & 1, flat >> 3);
}

// sigxg (z<128) ∥ Y_{prev} (z in 128..191)
__global__ __launch_bounds__(256) void k_sigxg_y(GemmP ps, GemmP px, GemmP py) {
    __shared__ __align__(16) ushort_t aT[64 * 64];
    __shared__ __align__(16) ushort_t bT[64 * 64];
    int z = blockIdx.z;
    if (z < 64)       gemm_body<64, 64, 3, EPI_SIG>(aT, bT, ps, blockIdx.x, blockIdx.y, z);
    else if (z < 128) gemm_body<64, 64, 0, EPI_XG>(aT, bT, px, blockIdx.x, blockIdx.y, z - 64);
    else              gemm_body<64, 64, 2, EPI_Y>(aT, bT, py, blockIdx.x, blockIdx.y, z - 128);
}

// ---------------- small kernels ----------------

// combine body: 5 bf16 split-K partials + bias -> bf16 fbuf (x8 elems/thread)
__device__ __forceinline__ void combine_body(int bid, const ushort_t* t,
                                             const float* fbias_s, ushort_t* f) {
    int idx = bid * 256 + threadIdx.x;
    const long long N = 16384ll * 256;
    ushort8 a0 = *(const ushort8*)(t + (long long)idx * 8);
    ushort8 a1 = *(const ushort8*)(t + N + (long long)idx * 8);
    ushort8 a2 = *(const ushort8*)(t + 2 * N + (long long)idx * 8);
    ushort8 a3 = *(const ushort8*)(t + 3 * N + (long long)idx * 8);
    ushort8 a4 = *(const ushort8*)(t + 4 * N + (long long)idx * 8);
    int cb = (idx * 8) & 255;
    ushort8 o;
#pragma unroll
    for (int k = 0; k < 8; ++k)
        o[k] = f2b(b2f(a0[k]) + b2f(a1[k]) + b2f(a2[k]) + b2f(a3[k]) + b2f(a4[k]) + fbias_s[cb + k]);
    *(ushort8*)&f[(long long)idx * 8] = o;
}

__global__ void k_combine(const ushort_t* __restrict__ t, const float* __restrict__ fbias_s,
                          ushort_t* __restrict__ f) {
    combine_body(blockIdx.x, t, fbias_s, f);
}

// combine_{s+1} (blocks < 2048) ∥ pscale_s (blocks 2048..2175)
__global__ __launch_bounds__(256) void k_comb_ps(const ushort_t* __restrict__ t,
                                                 const float* __restrict__ fbias_s,
                                                 ushort_t* __restrict__ f,
                                                 const ushort_t* __restrict__ q,
                                                 const float* __restrict__ dsum8,
                                                 float* __restrict__ dscale,
                                                 ushort_t* __restrict__ Pt) {
    int bid = blockIdx.x;
    if (bid < 2048) { combine_body(bid, t, fbias_s, f); return; }
    int pb = bid - 2048;                 // 0..127
    pscale_body(pb & 1, pb >> 1, q, dsum8, dscale, Pt);
}

// upsum body: x_sum = x_cur * (1 + bilinear_up2x_align_corners(x_lat))
__device__ __forceinline__ void upsum_body(void* smem, int b, int c0,
                                           const float* xc, const float* xl,
                                           ushort_t* xs) {
    float* lat = (float*)smem;                            // 64*64 f32 (16KB)
    ushort_t* tile = (ushort_t*)((char*)smem + 16384);    // 64*258 bf16 (33KB)
    int t = threadIdx.x;
    for (int i = t; i < 4096; i += 256)
        lat[i] = xl[((long long)(b * 1024 + c0 + (i >> 6))) * 64 + (i & 63)];
    __syncthreads();
    int y = t >> 4, x = t & 15;
    float fy = y * (7.f / 15.f); int y0 = (int)fy; float wy = fy - y0; int y1 = y0 + 1 > 7 ? 7 : y0 + 1;
    float fx = x * (7.f / 15.f); int x0 = (int)fx; float wx = fx - x0; int x1 = x0 + 1 > 7 ? 7 : x0 + 1;
    for (int cc = 0; cc < 64; ++cc) {
        float cur = xc[((long long)(b * 1024 + c0 + cc)) * 256 + t];
        const float* L = &lat[cc * 64];
        float tv = L[y0 * 8 + x0] * (1.f - wx) + L[y0 * 8 + x1] * wx;
        float bv = L[y1 * 8 + x0] * (1.f - wx) + L[y1 * 8 + x1] * wx;
        float up = tv + (bv - tv) * wy;
        tile[cc * 258 + t] = f2b(cur * (1.f + up));
    }
    __syncthreads();
    for (int i = t; i < 16384; i += 256) {
        int px = i >> 6, cc = i & 63;
        xs[((long long)(b * 256 + px)) * 1024 + c0 + cc] = tile[cc * 258 + px];
    }
}

__global__ void k_pscale(const ushort_t* __restrict__ q, const float* __restrict__ dsum8,
                         float* __restrict__ dscale, ushort_t* __restrict__ Pt) {
    pscale_body(blockIdx.x, blockIdx.y, q, dsum8, dscale, Pt);
}

// Prologue: weight/bias packing (blocks <1331) ∥ upsum (blocks 1331..2354).
// Independent: pack touches only weights, upsum only activations.
__global__ __launch_bounds__(256) void k_packup(
    const float* r0, const float* r1, const float* r2,
    const float* convw, const float* c1w, const float* c3w,
    const float* ckw, const float* gcnw,
    const float* rb0, const float* rb1, const float* rb2,
    const float* cb, const float* c1b, const float* ckbias,
    ushort_t* wbig3, ushort_t* wfq, ushort_t* w3b,
    ushort_t* gcnT, float* fqbias, float* fbias, ushort_t* zpage,
    const float* x_cur, const float* x_lat, ushort_t* xsum) {
    __shared__ __align__(16) char smem[49408];
    int blk = blockIdx.x, tid = threadIdx.x;
    if (blk >= 1331) {               // upsum role
        int u = blk - 1331;          // 0..1023
        upsum_body(smem, u & 63, (u >> 6) * 64, x_cur, x_lat, xsum);
        return;
    }
    if (blk < 768) {                 // wbig pack via LDS
        float* lw = (float*)smem;    // 10240 f32 = 40KB
        int s = blk >> 8, o = blk & 255;
        const float* rate = s == 0 ? r0 : (s == 1 ? r1 : r2);
        for (int i = tid; i < 9216; i += 256) lw[i] = rate[(long long)o * 9216 + i];
        for (int i = tid; i < 1024; i += 256) lw[9216 + i] = convw[(long long)o * 1024 + i];
        __syncthreads();
        ushort_t* dst = wbig3 + (long long)blk * 10240;
        for (int i = tid; i < 10240; i += 256) {
            int tap = i >> 10, ci = i & 1023;
            float v = (tap < 9) ? lw[ci * 9 + tap] : lw[9216 + ci];
            dst[i] = f2b(v);
        }
        return;
    }
    const int R1 = 262144;            // wfq: conv1_w part
    const int R2 = R1 + 32768;        // wfq: ck_w part
    const int R3 = R2 + 786432;       // w3b
    const int R4 = R3 + 65536;        // gcnT
    const int R5 = R4 + 1152;         // fqbias
    const int R6 = R5 + 768;          // fbias
    const int R7 = R6 + 4096;         // zpage
    int base = (blk - 768) * 2048 + tid * 8;
#pragma unroll
    for (int k = 0; k < 8; ++k) {
        int i = base + k;
        if (i >= R7) return;
        if (i < R1) wfq[i] = f2b(c1w[i]);
        else if (i < R2) wfq[i] = f2b(ckw[i - R1]);
        else if (i < R3) w3b[i - R2] = f2b(c3w[i - R2]);
        else if (i < R4) {
            int ii = i - R3; int c2 = ii >> 8, c1 = ii & 255;
            gcnT[ii] = f2b(gcnw[c1 * 256 + c2]);
        } else if (i < R5) {
            int ii = i - R4;
            fqbias[ii] = (ii < 1024) ? c1b[ii] : ckbias[ii - 1024];
        } else if (i < R6) {
            int ii = i - R5; int s = ii >> 8, t = ii & 255;
            const float* rb = s == 0 ? rb0 : (s == 1 ? rb1 : rb2);
            fbias[ii] = rb[t] + cb[t];
        } else {
            zpage[i - R6] = 0;
        }
    }
}

__global__ void k_sentinel(float* o, int n, float v) {
    int i = blockIdx.x * 256 + threadIdx.x; if (i < n) o[i] = v;
}

// ---------------- launch ----------------
extern "C" void kernel_launch(void* const* d_in, const int* in_sizes, int n_in,
                              void* d_out, int out_size, void* d_ws, size_t ws_size,
                              hipStream_t stream) {
    const float* x_cur  = (const float*)d_in[0];
    const float* x_lat  = (const float*)d_in[1];
    const float* conv_w = (const float*)d_in[2];
    const float* conv_b = (const float*)d_in[3];
    const float* conv1_w = (const float*)d_in[4];
    const float* conv1_b = (const float*)d_in[5];
    const float* conv3_w = (const float*)d_in[6];
    const float* conv3_b = (const float*)d_in[7];
    const float* rate_w[3] = {(const float*)d_in[8], (const float*)d_in[10], (const float*)d_in[12]};
    const float* rate_b[3] = {(const float*)d_in[9], (const float*)d_in[11], (const float*)d_in[13]};
    const float* ck_w  = (const float*)d_in[14];
    const float* ck_b  = (const float*)d_in[15];
    const float* avg_w = (const float*)d_in[16];
    const float* max_w = (const float*)d_in[17];
    const float* gcn_w = (const float*)d_in[18];
    float* out = (float*)d_out;

    char* w = (char*)d_ws;
    auto take = [&](size_t bytes) { void* p = (void*)w; w += (bytes + 255) & ~(size_t)255; return p; };
    ushort_t* xsum   = (ushort_t*)take(16384ll * 1024 * 2);    // 33.55MB
    ushort_t* feat   = (ushort_t*)take(16384ll * 1024 * 2);    // 33.55MB
    ushort_t* fbufP[2];                                        // stage-parity
    fbufP[0] = (ushort_t*)take(16384ll * 256 * 2);             // 8.39MB
    fbufP[1] = (ushort_t*)take(16384ll * 256 * 2);             // 8.39MB
    ushort_t* qbufP[2];
    qbufP[0] = (ushort_t*)take(16384ll * 128 * 2);             // 4.19MB
    qbufP[1] = (ushort_t*)take(16384ll * 128 * 2);             // 4.19MB
    ushort_t* xgt    = (ushort_t*)take(64ll * 256 * 256 * 2);  // 8.39MB
    ushort_t* Pt     = (ushort_t*)take(64ll * 128 * 256 * 2);  // 4.19MB
    ushort_t* Htn    = (ushort_t*)take(64ll * 256 * 128 * 2);  // 4.19MB
    ushort_t* wbig3  = (ushort_t*)take(3ll * 256 * 10240 * 2); // 15.73MB
    ushort_t* wfq    = (ushort_t*)take(1152ll * 256 * 2);
    ushort_t* w3b    = (ushort_t*)take(1024ll * 768 * 2);
    ushort_t* gcnT   = (ushort_t*)take(256ll * 256 * 2);
    ushort_t* zpage  = (ushort_t*)take(8192);
    float*    fqbias = (float*)take(1152 * 4);
    float*    fbias  = (float*)take(3 * 256 * 4);
    float*    cwbP[2];
    cwbP[0] = (float*)take(64 * 128 * 4);
    cwbP[1] = (float*)take(64 * 128 * 4);
    float*    dscale = (float*)take(64 * 256 * 4);
    float*    dsum8  = (float*)take(8ll * 64 * 256 * 4);
    ushort_t* catb   = (ushort_t*)take(16384ll * 768 * 2);     // 25.17MB
    ushort_t* ftmp   = (ushort_t*)take(5ll * 16384 * 256 * 2); // 41.94MB
    size_t need = (size_t)(w - (char*)d_ws);                   // ~195MB (<=204 proven)

    if (need > ws_size) {
        float v = 1.0e6f + (float)(ws_size >> 20);
        k_sentinel<<<(out_size + 255) / 256, 256, 0, stream>>>(out, out_size, v);
        return;
    }

    // per-stage GemmP builders
    auto PBIG = [&](int s) {
        GemmP p{};
        p.A = (s == 0) ? xsum : feat;
        p.B = wbig3 + (long long)s * 256 * 10240; p.ldb = 10240;
        p.Ksub = 2048; p.kSplit = 2048; p.dil = 1 << s;
        p.obf = ftmp; p.oBatch = 16384ll * 256;
        p.zpage = zpage;
        return p;
    };
    auto PSIG = [&](int s) {
        GemmP p{};
        p.A = qbufP[s & 1]; p.aBatch = 32768; p.lda = 128;
        p.B = qbufP[s & 1]; p.bBatch = 32768; p.ldb = 128;
        p.Ksub = 128; p.dsum = dsum8; p.cw = cwbP[s & 1];
        return p;
    };
    auto PXG = [&](int s) {
        GemmP p{};
        p.A = gcnT; p.aBatch = 0;            p.lda = 256;
        p.B = fbufP[s & 1]; p.bBatch = 65536; p.ldb = 256;
        p.Ksub = 256;
        p.obf = xgt; p.oBatch = 65536; p.ldo = 256;
        return p;
    };
    auto PHTN = [&](int s) {
        GemmP p{};
        p.A = xgt; p.aBatch = 65536; p.lda = 256;
        p.B = Pt;  p.bBatch = 32768; p.ldb = 256;
        p.Ksub = 256; p.cw = cwbP[s & 1];
        p.obf = Htn; p.oBatch = 32768; p.ldo = 128;
        return p;
    };
    auto PY = [&](int s) {
        GemmP p{};
        p.A = fbufP[s & 1]; p.aBatch = 65536; p.lda = 256;
        p.B = gcnT; p.bBatch = 0;             p.ldb = 256;
        p.A2 = qbufP[s & 1]; p.a2Batch = 32768; p.lda2 = 128; p.rscale = dscale;
        p.B2 = Htn;          p.b2Batch = 32768; p.ldb2 = 128;
        p.Ksub = 384;
        p.res = fbufP[s & 1]; p.resBatch = 65536; p.ldres = 256;
        p.obf = catb + s * 256; p.oBatch = 256ll * 768; p.ldo = 768;
        return p;
    };
    auto PFQ = [&](int s) {
        GemmP p{};
        p.A = fbufP[s & 1]; p.lda = 256; p.B = wfq; p.ldb = 256;
        p.Ksub = 256; p.bias = fqbias;
        p.res = xsum;
        p.obf = feat; p.obf2 = qbufP[s & 1];
        return p;
    };
    GemmP pz{};  // dummy for unused roles

    // 0: prologue — packall || upsum (independent; one dispatch)
    k_packup<<<768 + 563 + 1024, 256, 0, stream>>>(
        rate_w[0], rate_w[1], rate_w[2], conv_w, conv1_w, conv3_w, ck_w, gcn_w,
        rate_b[0], rate_b[1], rate_b[2], conv_b, conv1_b, ck_b,
        wbig3, wfq, w3b, gcnT, fqbias, fbias, zpage,
        x_cur, x_lat, xsum);

    // ---- software-pipelined schedule: stage-s GR tail rides inside stage-
    // (s+1) dispatches; combine_{s+1} || pscale_s fused ----
    // 1: BIG_0
    k_big_sig_y<<<dim3(128, 2, 5), 256, 0, stream>>>(PBIG(0), pz, pz, pz);
    // 2: combine_0
    k_combine<<<2048, 256, 0, stream>>>(ftmp, fbias + 0 * 256, fbufP[0]);
    // 3: FQ_0 + pool_0
    k_fqpool_htn<<<dim3(128, 10), 256, 0, stream>>>(PFQ(0), pz, avg_w, max_w, cwbP[0]);
    // 4: BIG_1 || sigxg_0
    k_big_sig_y<<<dim3(128, 2, 13), 256, 0, stream>>>(PBIG(1), PSIG(0), PXG(0), pz);
    // 5: combine_1 || pscale_0
    k_comb_ps<<<2048 + 128, 256, 0, stream>>>(ftmp, fbias + 1 * 256, fbufP[1],
                                              qbufP[0], dsum8, dscale, Pt);
    // 6: FQ_1 + pool_1 || Htn_0
    k_fqpool_htn<<<dim3(128, 14), 256, 0, stream>>>(PFQ(1), PHTN(0), avg_w, max_w, cwbP[1]);
    // 7: BIG_2 || sigxg_1 || Y_0
    k_big_sig_y<<<dim3(128, 2, 17), 256, 0, stream>>>(PBIG(2), PSIG(1), PXG(1), PY(0));
    // 8: combine_2 || pscale_1
    k_comb_ps<<<2048 + 128, 256, 0, stream>>>(ftmp, fbias + 2 * 256, fbufP[0],
                                              qbufP[1], dsum8, dscale, Pt);
    // 9: q_2 + pool_2 || Htn_1
    {
        GemmP pq{};
        pq.A = fbufP[0]; pq.lda = 256; pq.B = wfq + 1024 * 256; pq.ldb = 256;
        pq.Ksub = 256;
        pq.bias = ck_b; pq.obf = qbufP[0]; pq.ldo = 128;
        k_qpool_htn<<<dim3(256, 5), 256, 0, stream>>>(pq, PHTN(1), avg_w, max_w, cwbP[0]);
    }
    // 10: sigxg_2 || Y_1
    k_sigxg_y<<<dim3(4, 4, 192), 256, 0, stream>>>(PSIG(2), PXG(2), PY(1));
    // 11: pscale_2
    k_pscale<<<dim3(2, 64), 256, 0, stream>>>(qbufP[0], dsum8, dscale, Pt);
    // 12: Htn_2
    gemm_k<64, 64, 0, EPI_NEGCW><<<dim3(4, 2, 64), 256, 0, stream>>>(PHTN(2));
    // 13: Y_2
    gemm_k<64, 64, 2, EPI_Y><<<dim3(4, 4, 64), 256, 0, stream>>>(PY(2));
    // 14: OUT = cat @ w3^T + b — 128x128 tiles
    {
        GemmP p{};
        p.A = w3b;  p.lda = 768;
        p.B = catb; p.ldb = 768;
        p.Ksub = 768; p.bias = conv3_b; p.of32 = out;
        gemm_k<128, 128, 0, EPI_OUTT><<<dim3(8, 128, 1), 256, 0, stream>>>(p);
    }
}